// Round 1
// baseline (6917.027 us; speedup 1.0000x reference)
//
#include <hip/hip_runtime.h>

#define B_ 64
#define R_ 196
#define F_ 2048
#define E_ 512
#define H_ 512
#define A_ 512
#define V_ 12000
#define L_ 24

#define TK 16

__device__ __forceinline__ float fast_tanh(float x) {
    float t = __expf(2.f * x);
    return 1.f - 2.f / (t + 1.f);
}
__device__ __forceinline__ float fast_sig(float x) {
    return 1.f / (1.f + __expf(-x));
}

// -------------------------------------------------------------------------
// Generic segmented GEMM: C[m,n] = sum_seg A_s[m,:Ks] @ W_s[n,:Ks]^T (+bias)
// A row-major (M,K), W row-major (N,K). 64x64 tile, 256 threads, 4x4 micro.
// grid.z = split-K chunks (kChunk each, multiple of TK); each z writes to
// C + z*zstride (no accumulation -> deterministic; caller reduces).
// M must be a multiple of 64. Segment K sizes must be multiples of TK.
// -------------------------------------------------------------------------
__global__ __launch_bounds__(256) void gemm3(
    const float* __restrict__ A0, int lda0, int k0, const float* __restrict__ W0, int ldw0,
    const float* __restrict__ A1, int lda1, int k1, const float* __restrict__ W1, int ldw1,
    const float* __restrict__ A2, int lda2, int k2, const float* __restrict__ W2, int ldw2,
    const float* __restrict__ bias,
    float* __restrict__ C, int ldc, long zstride,
    int N, int kChunk)
{
    __shared__ float As[TK][68];
    __shared__ float Ws[TK][68];
    const int tid = threadIdx.x;
    const int ntile = blockIdx.x * 64;
    const int mtile = blockIdx.y * 64;
    const int kStart = blockIdx.z * kChunk;
    const int kEnd = kStart + kChunk;

    const int tx = tid & 15, ty = tid >> 4;
    const int lm = tid >> 2, kq = tid & 3;

    float acc[4][4] = {{0.f}};

    for (int g = kStart; g < kEnd; g += TK) {
        const float* Ab; int lda; const float* Wb; int ldw; int loc;
        if (g < k0)           { Ab = A0; lda = lda0; Wb = W0; ldw = ldw0; loc = g; }
        else if (g < k0 + k1) { Ab = A1; lda = lda1; Wb = W1; ldw = ldw1; loc = g - k0; }
        else                  { Ab = A2; lda = lda2; Wb = W2; ldw = ldw2; loc = g - k0 - k1; }

        const float4 av = *reinterpret_cast<const float4*>(
            Ab + (size_t)(mtile + lm) * lda + loc + kq * 4);
        const int wn = ntile + lm;
        float4 wv = make_float4(0.f, 0.f, 0.f, 0.f);
        if (wn < N)
            wv = *reinterpret_cast<const float4*>(
                Wb + (size_t)wn * ldw + loc + kq * 4);

        __syncthreads();
        As[kq * 4 + 0][lm] = av.x; As[kq * 4 + 1][lm] = av.y;
        As[kq * 4 + 2][lm] = av.z; As[kq * 4 + 3][lm] = av.w;
        Ws[kq * 4 + 0][lm] = wv.x; Ws[kq * 4 + 1][lm] = wv.y;
        Ws[kq * 4 + 2][lm] = wv.z; Ws[kq * 4 + 3][lm] = wv.w;
        __syncthreads();

        #pragma unroll
        for (int k = 0; k < TK; ++k) {
            const float4 a4 = *reinterpret_cast<const float4*>(&As[k][ty * 4]);
            const float4 w4 = *reinterpret_cast<const float4*>(&Ws[k][tx * 4]);
            const float am[4] = {a4.x, a4.y, a4.z, a4.w};
            const float wm[4] = {w4.x, w4.y, w4.z, w4.w};
            #pragma unroll
            for (int i = 0; i < 4; ++i)
                #pragma unroll
                for (int j = 0; j < 4; ++j)
                    acc[i][j] = fmaf(am[i], wm[j], acc[i][j]);
        }
    }

    float* Cz = C + (size_t)blockIdx.z * zstride;
    #pragma unroll
    for (int i = 0; i < 4; ++i) {
        const int m = mtile + ty * 4 + i;
        #pragma unroll
        for (int j = 0; j < 4; ++j) {
            const int n = ntile + tx * 4 + j;
            if (n < N) {
                float v = acc[i][j];
                if (bias) v += bias[n];
                Cz[(size_t)m * ldc + n] = v;
            }
        }
    }
}

// mean over regions: meanf[b,f] = mean_r feats[b,r,f]   (float4 over f)
__global__ __launch_bounds__(256) void mean_kernel(
    const float* __restrict__ feats, float* __restrict__ meanf)
{
    const int idx = blockIdx.x * 256 + threadIdx.x;   // B*F/4 = 32768
    const int b = idx >> 9, j = idx & 511;
    const float4* fp = reinterpret_cast<const float4*>(feats) + (size_t)b * R_ * (F_ / 4) + j;
    float4 acc = make_float4(0.f, 0.f, 0.f, 0.f);
    for (int r = 0; r < R_; ++r) {
        const float4 v = fp[(size_t)r * (F_ / 4)];
        acc.x += v.x; acc.y += v.y; acc.z += v.z; acc.w += v.w;
    }
    const float s = 1.f / (float)R_;
    acc.x *= s; acc.y *= s; acc.z *= s; acc.w *= s;
    reinterpret_cast<float4*>(meanf)[idx] = acc;
}

// gather embeddings for all timesteps: emb_seq[b,t,:] = emb_table[cap[b,t],:]
__global__ __launch_bounds__(256) void gather_kernel(
    const float* __restrict__ emb, const int* __restrict__ cap,
    float* __restrict__ emb_seq)
{
    const int idx = blockIdx.x * 256 + threadIdx.x;   // B*L*E/4 = 196608
    const int bt = idx >> 7, j = idx & 127;
    const int tok = cap[bt];
    reinterpret_cast<float4*>(emb_seq)[idx] =
        reinterpret_cast<const float4*>(emb)[(size_t)tok * (E_ / 4) + j];
}

// fused per-step attention: hid_proj -> scores(tanh) -> softmax -> alpha
// one block per batch element
__global__ __launch_bounds__(256) void attn_kernel(
    const float* __restrict__ h, const float* __restrict__ W_hidp,
    const float* __restrict__ b_hidp, const float* __restrict__ feat_proj,
    const float* __restrict__ W_score, const float* __restrict__ b_score,
    float* __restrict__ alpha, float* __restrict__ alph_out, int t)
{
    __shared__ float sh_h[H_];
    __shared__ float sh_ws[A_];
    __shared__ float sh_hp[A_];
    __shared__ float sh_sc[R_];
    __shared__ float red[2];
    const int tid = threadIdx.x;
    const int b = blockIdx.x;

    for (int i = tid; i < H_; i += 256) sh_h[i] = h[b * H_ + i];
    for (int i = tid; i < A_; i += 256) sh_ws[i] = W_score[i];
    __syncthreads();

    // hid_proj[a] = h[b,:] . W_hidp[a,:] + b_hidp[a]
    for (int a = tid; a < A_; a += 256) {
        const float4* wr = reinterpret_cast<const float4*>(W_hidp + (size_t)a * H_);
        float acc = 0.f;
        #pragma unroll 4
        for (int kk = 0; kk < H_ / 4; ++kk) {
            const float4 w = wr[kk];
            acc += w.x * sh_h[kk * 4 + 0] + w.y * sh_h[kk * 4 + 1]
                 + w.z * sh_h[kk * 4 + 2] + w.w * sh_h[kk * 4 + 3];
        }
        sh_hp[a] = acc + b_hidp[a];
    }
    __syncthreads();

    // scores[r] = sum_a tanh(feat_proj[b,r,a] + hid_proj[a]) * w_score[a]
    const int lane = tid & 63, wid = tid >> 6;
    for (int r = wid; r < R_; r += 4) {
        const float* fp = feat_proj + ((size_t)b * R_ + r) * A_;
        float acc = 0.f;
        for (int a = lane; a < A_; a += 64)
            acc += fast_tanh(fp[a] + sh_hp[a]) * sh_ws[a];
        for (int off = 32; off > 0; off >>= 1) acc += __shfl_down(acc, off);
        if (lane == 0) sh_sc[r] = acc + b_score[0];
    }
    __syncthreads();

    // softmax over R
    if (tid < 64) {
        float m = -1e30f;
        for (int r = tid; r < R_; r += 64) m = fmaxf(m, sh_sc[r]);
        for (int off = 32; off > 0; off >>= 1) m = fmaxf(m, __shfl_xor(m, off));
        float s = 0.f;
        for (int r = tid; r < R_; r += 64) s += __expf(sh_sc[r] - m);
        for (int off = 32; off > 0; off >>= 1) s += __shfl_xor(s, off);
        if (tid == 0) { red[0] = m; red[1] = 1.f / s; }
    }
    __syncthreads();
    const float m = red[0], is = red[1];
    for (int r = tid; r < R_; r += 256) {
        const float av = __expf(sh_sc[r] - m) * is;
        alpha[b * R_ + r] = av;
        alph_out[((size_t)b * L_ + t) * R_ + r] = av;
    }
}

// context[b,f] = sum_r alpha[b,r] * feats[b,r,f]   (float4 over f)
__global__ __launch_bounds__(256) void context_kernel(
    const float* __restrict__ feats, const float* __restrict__ alpha,
    float* __restrict__ ctx)
{
    const int idx = blockIdx.x * 256 + threadIdx.x;   // 32768
    const int b = idx >> 9, j = idx & 511;
    __shared__ float sa[R_];
    for (int r = threadIdx.x; r < R_; r += 256) sa[r] = alpha[b * R_ + r];
    __syncthreads();
    const float4* fp = reinterpret_cast<const float4*>(feats) + (size_t)b * R_ * (F_ / 4) + j;
    float4 acc = make_float4(0.f, 0.f, 0.f, 0.f);
    for (int r = 0; r < R_; ++r) {
        const float a = sa[r];
        const float4 v = fp[(size_t)r * (F_ / 4)];
        acc.x = fmaf(a, v.x, acc.x); acc.y = fmaf(a, v.y, acc.y);
        acc.z = fmaf(a, v.z, acc.z); acc.w = fmaf(a, v.w, acc.w);
    }
    reinterpret_cast<float4*>(ctx)[idx] = acc;
}

// LSTM cell: reduce split-K gate partials + biases, update h,c in place
__global__ __launch_bounds__(256) void cell_kernel(
    const float* __restrict__ gparts, const float* __restrict__ b_ih,
    const float* __restrict__ b_hh, float* __restrict__ h, float* __restrict__ c)
{
    const int idx = blockIdx.x * 256 + threadIdx.x;   // B*H = 32768
    const int b = idx >> 9, n = idx & 511;
    float gi = b_ih[n] + b_hh[n];
    float gf = b_ih[n + 512] + b_hh[n + 512];
    float gg = b_ih[n + 1024] + b_hh[n + 1024];
    float go = b_ih[n + 1536] + b_hh[n + 1536];
    #pragma unroll
    for (int z = 0; z < 4; ++z) {
        const float* gz = gparts + (size_t)z * B_ * 2048 + (size_t)b * 2048;
        gi += gz[n]; gf += gz[n + 512]; gg += gz[n + 1024]; go += gz[n + 1536];
    }
    const float cc = fast_sig(gf) * c[idx] + fast_sig(gi) * fast_tanh(gg);
    const float hh = fast_sig(go) * fast_tanh(cc);
    c[idx] = cc;
    h[idx] = hh;
}

extern "C" void kernel_launch(void* const* d_in, const int* in_sizes, int n_in,
                              void* d_out, int out_size, void* d_ws, size_t ws_size,
                              hipStream_t stream)
{
    const float* feats    = (const float*)d_in[0];
    const int*   cap      = (const int*)  d_in[1];
    const float* emb      = (const float*)d_in[2];
    const float* W_init_h = (const float*)d_in[3];
    const float* b_init_h = (const float*)d_in[4];
    const float* W_init_c = (const float*)d_in[5];
    const float* b_init_c = (const float*)d_in[6];
    const float* W_ih     = (const float*)d_in[7];
    const float* b_ih     = (const float*)d_in[8];
    const float* W_hh     = (const float*)d_in[9];
    const float* b_hh     = (const float*)d_in[10];
    const float* W_featp  = (const float*)d_in[11];
    const float* b_featp  = (const float*)d_in[12];
    const float* W_hidp   = (const float*)d_in[13];
    const float* b_hidp   = (const float*)d_in[14];
    const float* W_score  = (const float*)d_in[15];
    const float* b_score  = (const float*)d_in[16];
    const float* W_out    = (const float*)d_in[17];
    const float* b_out    = (const float*)d_in[18];

    float* pred     = (float*)d_out;                          // (B,L,V)
    float* alph_out = pred + (size_t)B_ * L_ * V_;            // (B,L,R)

    float* ws = (float*)d_ws;
    float* feat_proj = ws; ws += (size_t)B_ * R_ * A_;        // 6.42M
    float* emb_seq   = ws; ws += (size_t)B_ * L_ * E_;        // 786K
    float* meanf     = ws; ws += B_ * F_;
    float* h         = ws; ws += B_ * H_;
    float* c         = ws; ws += B_ * H_;
    float* alpha     = ws; ws += B_ * R_;
    float* ctx       = ws; ws += B_ * F_;
    float* gparts    = ws; ws += 4 * B_ * 4 * H_;             // split-K=4 partials

    // ---- one-time prep ----
    mean_kernel<<<128, 256, 0, stream>>>(feats, meanf);
    gather_kernel<<<768, 256, 0, stream>>>(emb, cap, emb_seq);

    // h0 = meanf @ W_init_h.T + b ; c0 likewise
    gemm3<<<dim3(8, 1, 1), 256, 0, stream>>>(
        meanf, F_, F_, W_init_h, F_,
        nullptr, 0, 0, nullptr, 0,  nullptr, 0, 0, nullptr, 0,
        b_init_h, h, H_, 0, H_, F_);
    gemm3<<<dim3(8, 1, 1), 256, 0, stream>>>(
        meanf, F_, F_, W_init_c, F_,
        nullptr, 0, 0, nullptr, 0,  nullptr, 0, 0, nullptr, 0,
        b_init_c, c, H_, 0, H_, F_);

    // feat_proj = image_feats(12544,2048) @ W_featp.T + b_featp
    gemm3<<<dim3(8, 196, 1), 256, 0, stream>>>(
        feats, F_, F_, W_featp, F_,
        nullptr, 0, 0, nullptr, 0,  nullptr, 0, 0, nullptr, 0,
        b_featp, feat_proj, A_, 0, A_, F_);

    // ---- sequential decode ----
    for (int t = 0; t < L_; ++t) {
        attn_kernel<<<B_, 256, 0, stream>>>(
            h, W_hidp, b_hidp, feat_proj, W_score, b_score, alpha, alph_out, t);

        context_kernel<<<128, 256, 0, stream>>>(feats, alpha, ctx);

        // gates partials: [emb_t | ctx | h] against [W_ih[:,:E] | W_ih[:,E:] | W_hh]
        gemm3<<<dim3(32, 1, 4), 256, 0, stream>>>(
            emb_seq + (size_t)t * E_, L_ * E_, E_, W_ih, E_ + F_,
            ctx, F_, F_, W_ih + E_, E_ + F_,
            h, H_, H_, W_hh, H_,
            nullptr, gparts, 4 * H_, (long)B_ * 4 * H_,
            4 * H_, (E_ + F_ + H_) / 4);

        cell_kernel<<<128, 256, 0, stream>>>(gparts, b_ih, b_hh, h, c);

        // predictions[:,t,:] = h_new @ W_out.T + b_out
        gemm3<<<dim3(188, 1, 1), 256, 0, stream>>>(
            h, H_, H_, W_out, H_,
            nullptr, 0, 0, nullptr, 0,  nullptr, 0, 0, nullptr, 0,
            b_out, pred + (size_t)t * V_, L_ * V_, 0, V_, H_);
    }
}

// Round 2
// 3275.303 us; speedup vs baseline: 2.1119x; 2.1119x over previous
//
#include <hip/hip_runtime.h>

#define B_ 64
#define R_ 196
#define F_ 2048
#define E_ 512
#define H_ 512
#define A_ 512
#define V_ 12000
#define L_ 24

typedef __attribute__((ext_vector_type(8))) short bf16x8;
typedef __attribute__((ext_vector_type(4))) float f32x4;

__device__ __forceinline__ float fast_tanh(float x) {
    float t = __expf(2.f * x);
    return 1.f - 2.f / (t + 1.f);
}
__device__ __forceinline__ float fast_sig(float x) {
    return 1.f / (1.f + __expf(-x));
}
__device__ __forceinline__ unsigned short f2bf(float x) {
    unsigned int u = __float_as_uint(x);
    unsigned int r = (u + 0x7fffu + ((u >> 16) & 1u)) >> 16;
    return (unsigned short)r;
}
__device__ __forceinline__ float bf2f(unsigned short b) {
    return __uint_as_float(((unsigned int)b) << 16);
}

// ---------------------------------------------------------------------------
// MFMA GEMM: C[m,n] = sum_seg A_s[m,:Ks] @ W_s[n,:Ks]^T (+bias), bf16 inputs.
// SPLIT=3: A,W given as (hi,lo) bf16 pairs -> 3 MFMAs (hi*hi+hi*lo+lo*hi),
//          near-fp32 accuracy. SPLIT=1: hi only.
// Tile 64x64, BK=32, 256 threads (4 waves, wave w owns n-cols [16w,16w+16)).
// grid.z = split-K chunks of kChunk (multiple of 32); z writes C + z*zstride.
// M multiple of 64 (grid.y). N masked. Segment K sizes multiples of 32.
// ---------------------------------------------------------------------------
#define LROW 40   // LDS row stride in bf16 elems (32 + 8 pad -> conflict-free-ish)

template<int SPLIT, bool OUTBF>
__global__ __launch_bounds__(256) void gemm_mfma(
    const unsigned short* __restrict__ Ah0, const unsigned short* __restrict__ Al0, int lda0, int k0,
    const unsigned short* __restrict__ Ah1, const unsigned short* __restrict__ Al1, int lda1, int k1,
    const unsigned short* __restrict__ Ah2, const unsigned short* __restrict__ Al2, int lda2, int k2,
    const unsigned short* __restrict__ Wh, const unsigned short* __restrict__ Wl, int ldw,
    const float* __restrict__ bias,
    void* __restrict__ Cv, int ldc, long zstride, int N, int kChunk)
{
    __shared__ unsigned short sAh[64 * LROW];
    __shared__ unsigned short sBh[64 * LROW];
    __shared__ unsigned short sAl[64 * LROW];
    __shared__ unsigned short sBl[64 * LROW];

    const int tid = threadIdx.x;
    const int ntile = blockIdx.x * 64;
    const int mtile = blockIdx.y * 64;
    const int kStart = blockIdx.z * kChunk;
    const int lane = tid & 63, w = tid >> 6;
    const int lrow = tid >> 2;            // staging row 0..63
    const int lcol = (tid & 3) * 8;       // staging k-offset (bf16 elems)
    const int nrow = ntile + lrow;
    const bool nok = nrow < N;

    f32x4 acc[4];
    #pragma unroll
    for (int f = 0; f < 4; ++f) acc[f] = {0.f, 0.f, 0.f, 0.f};

    const int fr = lane & 15;
    const int kg = (lane >> 4) * 8;

    for (int kb = kStart; kb < kStart + kChunk; kb += 32) {
        const unsigned short *ph, *pl; int lda, loc;
        if (kb < k0)           { ph = Ah0; pl = Al0; lda = lda0; loc = kb; }
        else if (kb < k0 + k1) { ph = Ah1; pl = Al1; lda = lda1; loc = kb - k0; }
        else                   { ph = Ah2; pl = Al2; lda = lda2; loc = kb - k0 - k1; }

        const uint4 zv = make_uint4(0u, 0u, 0u, 0u);
        uint4 a_h = *(const uint4*)(ph + (size_t)(mtile + lrow) * lda + loc + lcol);
        uint4 b_h = nok ? *(const uint4*)(Wh + (size_t)nrow * ldw + kb + lcol) : zv;
        uint4 a_l, b_l;
        if constexpr (SPLIT == 3) {
            a_l = *(const uint4*)(pl + (size_t)(mtile + lrow) * lda + loc + lcol);
            b_l = nok ? *(const uint4*)(Wl + (size_t)nrow * ldw + kb + lcol) : zv;
        }

        __syncthreads();
        *(uint4*)(sAh + lrow * LROW + lcol) = a_h;
        *(uint4*)(sBh + lrow * LROW + lcol) = b_h;
        if constexpr (SPLIT == 3) {
            *(uint4*)(sAl + lrow * LROW + lcol) = a_l;
            *(uint4*)(sBl + lrow * LROW + lcol) = b_l;
        }
        __syncthreads();

        const bf16x8 bh = *(const bf16x8*)(sBh + (16 * w + fr) * LROW + kg);
        bf16x8 bl;
        if constexpr (SPLIT == 3) bl = *(const bf16x8*)(sBl + (16 * w + fr) * LROW + kg);

        #pragma unroll
        for (int f = 0; f < 4; ++f) {
            const bf16x8 ah = *(const bf16x8*)(sAh + (16 * f + fr) * LROW + kg);
            acc[f] = __builtin_amdgcn_mfma_f32_16x16x32_bf16(ah, bh, acc[f], 0, 0, 0);
            if constexpr (SPLIT == 3) {
                const bf16x8 al = *(const bf16x8*)(sAl + (16 * f + fr) * LROW + kg);
                acc[f] = __builtin_amdgcn_mfma_f32_16x16x32_bf16(ah, bl, acc[f], 0, 0, 0);
                acc[f] = __builtin_amdgcn_mfma_f32_16x16x32_bf16(al, bh, acc[f], 0, 0, 0);
            }
        }
    }

    // epilogue: D col = lane&15, row = (lane>>4)*4 + reg
    const int n = ntile + 16 * w + (lane & 15);
    if (n < N) {
        const float bv = bias ? bias[n] : 0.f;
        #pragma unroll
        for (int f = 0; f < 4; ++f) {
            #pragma unroll
            for (int r = 0; r < 4; ++r) {
                const int m = mtile + 16 * f + (lane >> 4) * 4 + r;
                const float v = acc[f][r] + bv;
                if constexpr (OUTBF)
                    ((unsigned short*)Cv)[(size_t)m * ldc + n] = f2bf(v);
                else
                    ((float*)Cv + (size_t)blockIdx.z * zstride)[(size_t)m * ldc + n] = v;
            }
        }
    }
}

// mean over regions -> bf16 hi/lo
__global__ __launch_bounds__(256) void mean_split(
    const float* __restrict__ feats, unsigned short* __restrict__ mh,
    unsigned short* __restrict__ ml)
{
    const int idx = blockIdx.x * 256 + threadIdx.x;   // B*F/4 = 32768
    const int b = idx >> 9, j = idx & 511;
    const float4* fp = reinterpret_cast<const float4*>(feats) + (size_t)b * R_ * (F_ / 4) + j;
    float4 acc = make_float4(0.f, 0.f, 0.f, 0.f);
    for (int r = 0; r < R_; ++r) {
        const float4 v = fp[(size_t)r * (F_ / 4)];
        acc.x += v.x; acc.y += v.y; acc.z += v.z; acc.w += v.w;
    }
    const float s = 1.f / (float)R_;
    const float a[4] = {acc.x * s, acc.y * s, acc.z * s, acc.w * s};
    #pragma unroll
    for (int c = 0; c < 4; ++c) {
        const unsigned short hi = f2bf(a[c]);
        mh[idx * 4 + c] = hi;
        ml[idx * 4 + c] = f2bf(a[c] - bf2f(hi));
    }
}

// gather embeddings -> bf16 hi/lo (B,L,E)
__global__ __launch_bounds__(256) void gather_split(
    const float* __restrict__ emb, const int* __restrict__ cap,
    unsigned short* __restrict__ eh, unsigned short* __restrict__ el)
{
    const int idx = blockIdx.x * 256 + threadIdx.x;   // B*L*E/4 = 196608
    const int bt = idx >> 7, j = idx & 127;
    const int tok = cap[bt];
    const float4 v = reinterpret_cast<const float4*>(emb)[(size_t)tok * (E_ / 4) + j];
    const float a[4] = {v.x, v.y, v.z, v.w};
    #pragma unroll
    for (int c = 0; c < 4; ++c) {
        const unsigned short hi = f2bf(a[c]);
        eh[idx * 4 + c] = hi;
        el[idx * 4 + c] = f2bf(a[c] - bf2f(hi));
    }
}

// generic fp32 -> bf16 (hi, optional lo), grid-stride over float4s
__global__ __launch_bounds__(256) void split_kernel(
    const float* __restrict__ in, unsigned short* __restrict__ hi,
    unsigned short* __restrict__ lo, int n4)
{
    for (int i = blockIdx.x * 256 + threadIdx.x; i < n4; i += gridDim.x * 256) {
        const float4 v = reinterpret_cast<const float4*>(in)[i];
        const float a[4] = {v.x, v.y, v.z, v.w};
        #pragma unroll
        for (int c = 0; c < 4; ++c) {
            const unsigned short h = f2bf(a[c]);
            hi[i * 4 + c] = h;
            if (lo) lo[i * 4 + c] = f2bf(a[c] - bf2f(h));
        }
    }
}

// Wg[n][0:2560] = W_ih[n], Wg[n][2560:3072] = W_hh[n]; split hi/lo
__global__ __launch_bounds__(256) void concat_split(
    const float* __restrict__ W_ih, const float* __restrict__ W_hh,
    unsigned short* __restrict__ gh, unsigned short* __restrict__ gl)
{
    const int nrow = blockIdx.x;   // 2048
    for (int k = threadIdx.x; k < 3072; k += 256) {
        const float v = (k < 2560) ? W_ih[(size_t)nrow * 2560 + k]
                                   : W_hh[(size_t)nrow * 512 + (k - 2560)];
        const unsigned short h = f2bf(v);
        gh[(size_t)nrow * 3072 + k] = h;
        gl[(size_t)nrow * 3072 + k] = f2bf(v - bf2f(h));
    }
}

// fused attention: hid_proj -> scores(tanh, bf16 feat_proj) -> softmax ->
// context quarter (rs = blockIdx.x selects f-range), ctx written as bf16 hi/lo
__global__ __launch_bounds__(256) void attn_ctx(
    const float* __restrict__ h, const float* __restrict__ W_hidp,
    const float* __restrict__ b_hidp, const unsigned short* __restrict__ fpb,
    const float* __restrict__ W_score, const float* __restrict__ b_score,
    const float* __restrict__ feats, float* __restrict__ alph_out,
    unsigned short* __restrict__ ctx_hi, unsigned short* __restrict__ ctx_lo, int t)
{
    __shared__ float sh_h[H_];
    __shared__ float sh_hp[A_];
    __shared__ float sh_ws[A_];
    __shared__ float sh_sc[200];
    __shared__ float red[2];
    const int tid = threadIdx.x;
    const int rs = blockIdx.x;     // 0..3 f-quarter
    const int b = blockIdx.y;

    sh_h[tid] = h[b * H_ + tid];
    sh_h[tid + 256] = h[b * H_ + 256 + tid];
    sh_ws[tid] = W_score[tid];
    sh_ws[tid + 256] = W_score[tid + 256];
    __syncthreads();

    for (int a = tid; a < A_; a += 256) {
        const float4* wr = reinterpret_cast<const float4*>(W_hidp + (size_t)a * H_);
        float acc = 0.f;
        #pragma unroll 8
        for (int kk = 0; kk < H_ / 4; ++kk) {
            const float4 w4 = wr[kk];
            acc += w4.x * sh_h[kk * 4 + 0] + w4.y * sh_h[kk * 4 + 1]
                 + w4.z * sh_h[kk * 4 + 2] + w4.w * sh_h[kk * 4 + 3];
        }
        sh_hp[a] = acc + b_hidp[a];
    }
    __syncthreads();

    const int lane = tid & 63, wid = tid >> 6;
    for (int r = wid; r < R_; r += 4) {
        const ushort2* row = reinterpret_cast<const ushort2*>(fpb + ((size_t)b * R_ + r) * A_);
        float acc = 0.f;
        #pragma unroll
        for (int j = 0; j < 4; ++j) {
            const ushort2 u = row[lane + 64 * j];
            const int a = 2 * (lane + 64 * j);
            acc += fast_tanh(bf2f(u.x) + sh_hp[a]) * sh_ws[a];
            acc += fast_tanh(bf2f(u.y) + sh_hp[a + 1]) * sh_ws[a + 1];
        }
        for (int off = 32; off > 0; off >>= 1) acc += __shfl_down(acc, off);
        if (lane == 0) sh_sc[r] = acc + b_score[0];
    }
    __syncthreads();

    if (tid < 64) {
        float m = -1e30f;
        for (int r = tid; r < R_; r += 64) m = fmaxf(m, sh_sc[r]);
        for (int off = 32; off > 0; off >>= 1) m = fmaxf(m, __shfl_xor(m, off));
        float s = 0.f;
        for (int r = tid; r < R_; r += 64) s += __expf(sh_sc[r] - m);
        for (int off = 32; off > 0; off >>= 1) s += __shfl_xor(s, off);
        if (tid == 0) { red[0] = m; red[1] = 1.f / s; }
    }
    __syncthreads();
    const float m = red[0], is = red[1];
    if (tid < R_) {
        const float av = __expf(sh_sc[tid] - m) * is;
        sh_sc[tid] = av;
        if (rs == 0) alph_out[((size_t)b * L_ + t) * R_ + tid] = av;
    }
    __syncthreads();

    // context quarter: f in [rs*512, rs*512+512)
    const int f0 = rs * 512 + tid * 2;
    const float2* fp = reinterpret_cast<const float2*>(feats + (size_t)b * R_ * F_ + f0);
    float cx = 0.f, cy = 0.f;
    #pragma unroll 4
    for (int r = 0; r < R_; ++r) {
        const float a = sh_sc[r];
        const float2 v = fp[(size_t)r * (F_ / 2)];
        cx = fmaf(a, v.x, cx); cy = fmaf(a, v.y, cy);
    }
    const size_t ci = (size_t)b * F_ + f0;
    const unsigned short hx = f2bf(cx);
    ctx_hi[ci] = hx; ctx_lo[ci] = f2bf(cx - bf2f(hx));
    const unsigned short hy = f2bf(cy);
    ctx_hi[ci + 1] = hy; ctx_lo[ci + 1] = f2bf(cy - bf2f(hy));
}

// LSTM cell: reduce 8 split-K gate partials + biases, update h,c; h -> hi/lo
__global__ __launch_bounds__(256) void cell_kernel(
    const float* __restrict__ gparts, const float* __restrict__ b_ih,
    const float* __restrict__ b_hh, float* __restrict__ h, float* __restrict__ c,
    unsigned short* __restrict__ h_hi, unsigned short* __restrict__ h_lo)
{
    const int idx = blockIdx.x * 256 + threadIdx.x;   // B*H = 32768
    const int b = idx >> 9, n = idx & 511;
    float gi = b_ih[n] + b_hh[n];
    float gf = b_ih[n + 512] + b_hh[n + 512];
    float gg = b_ih[n + 1024] + b_hh[n + 1024];
    float go = b_ih[n + 1536] + b_hh[n + 1536];
    #pragma unroll
    for (int z = 0; z < 8; ++z) {
        const float* gz = gparts + (size_t)z * B_ * 2048 + (size_t)b * 2048;
        gi += gz[n]; gf += gz[n + 512]; gg += gz[n + 1024]; go += gz[n + 1536];
    }
    const float cc = fast_sig(gf) * c[idx] + fast_sig(gi) * fast_tanh(gg);
    const float hh = fast_sig(go) * fast_tanh(cc);
    c[idx] = cc;
    h[idx] = hh;
    const unsigned short hi = f2bf(hh);
    h_hi[idx] = hi;
    h_lo[idx] = f2bf(hh - bf2f(hi));
}

extern "C" void kernel_launch(void* const* d_in, const int* in_sizes, int n_in,
                              void* d_out, int out_size, void* d_ws, size_t ws_size,
                              hipStream_t stream)
{
    const float* feats    = (const float*)d_in[0];
    const int*   cap      = (const int*)  d_in[1];
    const float* emb      = (const float*)d_in[2];
    const float* W_init_h = (const float*)d_in[3];
    const float* b_init_h = (const float*)d_in[4];
    const float* W_init_c = (const float*)d_in[5];
    const float* b_init_c = (const float*)d_in[6];
    const float* W_ih     = (const float*)d_in[7];
    const float* b_ih     = (const float*)d_in[8];
    const float* W_hh     = (const float*)d_in[9];
    const float* b_hh     = (const float*)d_in[10];
    const float* W_featp  = (const float*)d_in[11];
    const float* b_featp  = (const float*)d_in[12];
    const float* W_hidp   = (const float*)d_in[13];
    const float* b_hidp   = (const float*)d_in[14];
    const float* W_score  = (const float*)d_in[15];
    const float* b_score  = (const float*)d_in[16];
    const float* W_out    = (const float*)d_in[17];
    const float* b_out    = (const float*)d_in[18];

    float* pred     = (float*)d_out;                          // (B,L,V)
    float* alph_out = pred + (size_t)B_ * L_ * V_;            // (B,L,R)

    char* p = (char*)d_ws;
    auto alloc = [&](size_t bytes) { char* q = p; p += (bytes + 255) & ~(size_t)255; return q; };
    typedef unsigned short ush;

    ush*   fpb   = (ush*)  alloc((size_t)B_ * R_ * A_ * 2);        // feat_proj bf16
    ush*   eh    = (ush*)  alloc((size_t)B_ * L_ * E_ * 2);
    ush*   el    = (ush*)  alloc((size_t)B_ * L_ * E_ * 2);
    ush*   mh    = (ush*)  alloc((size_t)B_ * F_ * 2);
    ush*   ml    = (ush*)  alloc((size_t)B_ * F_ * 2);
    ush*   fbh   = (ush*)  alloc((size_t)B_ * R_ * F_ * 2);        // feats bf16 (hi only)
    ush*   wfp_h = (ush*)  alloc((size_t)A_ * F_ * 2);
    ush*   wihh  = (ush*)  alloc((size_t)H_ * F_ * 2);
    ush*   wihl  = (ush*)  alloc((size_t)H_ * F_ * 2);
    ush*   wich  = (ush*)  alloc((size_t)H_ * F_ * 2);
    ush*   wicl  = (ush*)  alloc((size_t)H_ * F_ * 2);
    ush*   wgh   = (ush*)  alloc((size_t)2048 * 3072 * 2);
    ush*   wgl   = (ush*)  alloc((size_t)2048 * 3072 * 2);
    ush*   woh   = (ush*)  alloc((size_t)V_ * H_ * 2);
    ush*   wol   = (ush*)  alloc((size_t)V_ * H_ * 2);
    float* h     = (float*)alloc((size_t)B_ * H_ * 4);
    float* c     = (float*)alloc((size_t)B_ * H_ * 4);
    ush*   h_hi  = (ush*)  alloc((size_t)B_ * H_ * 2);
    ush*   h_lo  = (ush*)  alloc((size_t)B_ * H_ * 2);
    ush*   ctx_hi= (ush*)  alloc((size_t)B_ * F_ * 2);
    ush*   ctx_lo= (ush*)  alloc((size_t)B_ * F_ * 2);
    float* gparts= (float*)alloc((size_t)8 * B_ * 2048 * 4);

    // ---- one-time prep ----
    mean_split<<<128, 256, 0, stream>>>(feats, mh, ml);
    gather_split<<<768, 256, 0, stream>>>(emb, cap, eh, el);
    split_kernel<<<2048, 256, 0, stream>>>(W_out, woh, wol, V_ * H_ / 4);
    split_kernel<<<512, 256, 0, stream>>>(W_init_h, wihh, wihl, H_ * F_ / 4);
    split_kernel<<<512, 256, 0, stream>>>(W_init_c, wich, wicl, H_ * F_ / 4);
    split_kernel<<<512, 256, 0, stream>>>(W_featp, wfp_h, nullptr, A_ * F_ / 4);
    split_kernel<<<2048, 256, 0, stream>>>(feats, fbh, nullptr, B_ * R_ * F_ / 4);
    concat_split<<<2048, 256, 0, stream>>>(W_ih, W_hh, wgh, wgl);

    // h0 = mean @ W_init_h.T + b ; c0 likewise (bf16x2 MFMA)
    gemm_mfma<3, false><<<dim3(8, 1, 1), 256, 0, stream>>>(
        mh, ml, F_, F_, nullptr, nullptr, 0, 0, nullptr, nullptr, 0, 0,
        wihh, wihl, F_, b_init_h, h, H_, 0, H_, F_);
    gemm_mfma<3, false><<<dim3(8, 1, 1), 256, 0, stream>>>(
        mh, ml, F_, F_, nullptr, nullptr, 0, 0, nullptr, nullptr, 0, 0,
        wich, wicl, F_, b_init_c, c, H_, 0, H_, F_);
    split_kernel<<<32, 256, 0, stream>>>(h, h_hi, h_lo, B_ * H_ / 4);

    // feat_proj (bf16 single, bf16 out)
    gemm_mfma<1, true><<<dim3(8, 196, 1), 256, 0, stream>>>(
        fbh, nullptr, F_, F_, nullptr, nullptr, 0, 0, nullptr, nullptr, 0, 0,
        wfp_h, nullptr, F_, b_featp, fpb, A_, 0, A_, F_);

    // ---- sequential decode ----
    for (int t = 0; t < L_; ++t) {
        attn_ctx<<<dim3(4, B_), 256, 0, stream>>>(
            h, W_hidp, b_hidp, fpb, W_score, b_score, feats,
            alph_out, ctx_hi, ctx_lo, t);

        // gates: segments [emb_t | ctx | h] vs Wg, split-K=8 partials
        gemm_mfma<3, false><<<dim3(32, 1, 8), 256, 0, stream>>>(
            eh + (size_t)t * E_, el + (size_t)t * E_, L_ * E_, E_,
            ctx_hi, ctx_lo, F_, F_,
            h_hi, h_lo, H_, H_,
            wgh, wgl, E_ + F_ + H_, nullptr,
            gparts, 4 * H_, (long)B_ * 4 * H_, 4 * H_, (E_ + F_ + H_) / 8);

        cell_kernel<<<128, 256, 0, stream>>>(gparts, b_ih, b_hh, h, c, h_hi, h_lo);

        // predictions[:,t,:] = h @ W_out.T + b_out (bf16x2 MFMA)
        gemm_mfma<3, false><<<dim3(188, 1, 1), 256, 0, stream>>>(
            h_hi, h_lo, H_, H_, nullptr, nullptr, 0, 0, nullptr, nullptr, 0, 0,
            woh, wol, H_, b_out, pred + (size_t)t * V_, L_ * V_, 0, V_, H_);
    }
}